// Round 6
// baseline (3059.320 us; speedup 1.0000x reference)
//
#include <hip/hip_runtime.h>
#include <math.h>

#define WW 256
#define HH 256
#define DDP 96
#define HWP (WW*HH)            // 65536
#define DHW (DDP*HWP)          // 6291456 per volume
#define N2 (2*DHW)             // one branch tensor (B=2,C=1)
#define TX 64                  // x extent per block (32 threads x 2 px)
#define TY 8                   // y rows per block
#define NT 256
#define ZS 12
#define NSLAB (DDP/ZS)         // 8
#define RED_BLOCKS 1024
#define NITER 40

typedef unsigned int u32;
typedef unsigned short u16;

__device__ __forceinline__ float fmin3(float a, float b, float c) { return fminf(a, fminf(b, c)); }
__device__ __forceinline__ float fmax3(float a, float b, float c) { return fmaxf(a, fmaxf(b, c)); }
__device__ __forceinline__ float sigm(float x) { return 1.f / (1.f + expf(-x)); }

__device__ __forceinline__ float bf2f(u16 h) {
    u32 u = ((u32)h) << 16;
    return __builtin_bit_cast(float, u);
}
__device__ __forceinline__ u16 f2bf(float f) {  // round-to-nearest-even
    u32 u = __builtin_bit_cast(u32, f);
    return (u16)((u + 0x7fffu + ((u >> 16) & 1u)) >> 16);
}
__device__ __forceinline__ u32 pack2(float a, float b) {
    return (u32)f2bf(a) | ((u32)f2bf(b) << 16);
}

// Replicate-clamp loads: coordinate clamping replicates an element already inside
// window-intersect-volume, so first-level min AND max pooling stay exact.

// ---------------- init erosion: eout = E(f(fin)), f = sigmoid if DOSIG ----------------
template<bool DOSIG>
__global__ __launch_bounds__(NT) void erode_init_kernel(const float* __restrict__ fin,
                                                        u16* __restrict__ eout) {
    const int tx2 = threadIdx.x & 31;
    const int ty  = threadIdx.x >> 5;
    const int x0 = blockIdx.x * TX;
    const int y0 = blockIdx.y * TY;
    const int vol = blockIdx.z / NSLAB;
    const int z0 = (blockIdx.z % NSLAB) * ZS;
    const size_t base = (size_t)vol * DHW;
    const float* vin = fin + base;

    __shared__ float raw[TY + 2][TX + 4];
    __shared__ float mnx[TY + 2][TX];

    float q0[2], q1[2], q2[2];
    q0[0]=q0[1]=q1[0]=q1[1]=q2[0]=q2[1]=INFINITY;

    for (int zi = z0 - 1; zi <= z0 + ZS; ++zi) {
        const int zl = min(max(zi, 0), DDP - 1);
        const float* pl = vin + (size_t)zl * HWP;
        for (int i = threadIdx.x; i < (TY + 2) * ((TX + 4) / 2); i += NT) {
            int ry = i / ((TX + 4) / 2);
            int rx2 = i - ry * ((TX + 4) / 2);
            int gy = y0 + ry - 1; gy = min(max(gy, 0), HH - 1);
            int gx0 = x0 + 2 * rx2 - 2;
            float v0, v1;
            if (gx0 < 0)        { float t = pl[(size_t)gy * WW];          v0 = v1 = t; }
            else if (gx0 >= WW) { float t = pl[(size_t)gy * WW + WW - 1]; v0 = v1 = t; }
            else {
                float2 fv = *reinterpret_cast<const float2*>(pl + (size_t)gy * WW + gx0);
                v0 = fv.x; v1 = fv.y;
            }
            *reinterpret_cast<float2*>(&raw[ry][2 * rx2]) = make_float2(v0, v1);
        }
        __syncthreads();
        for (int i = threadIdx.x; i < (TY + 2) * TX; i += NT) {
            int ry = i >> 6;
            int rx = i & (TX - 1);
            mnx[ry][rx] = fmin3(raw[ry][rx + 1], raw[ry][rx + 2], raw[ry][rx + 3]);
        }
        __syncthreads();
        float2 m0 = *reinterpret_cast<float2*>(&mnx[ty][2 * tx2]);
        float2 m1 = *reinterpret_cast<float2*>(&mnx[ty + 1][2 * tx2]);
        float2 m2 = *reinterpret_cast<float2*>(&mnx[ty + 2][2 * tx2]);
        q0[0]=q1[0]; q1[0]=q2[0]; q2[0]=fmin3(m0.x, m1.x, m2.x);
        q0[1]=q1[1]; q1[1]=q2[1]; q2[1]=fmin3(m0.y, m1.y, m2.y);
        if (zi >= z0 + 1) {
            int zc = zi - 1;
            float v0 = fmin3(q0[0], q1[0], q2[0]);
            float v1 = fmin3(q0[1], q1[1], q2[1]);
            if (DOSIG) { v0 = sigm(v0); v1 = sigm(v1); }
            size_t idx = base + (size_t)zc * HWP + (size_t)(y0 + ty) * WW + x0 + 2 * tx2;
            *reinterpret_cast<u32*>(eout + idx) = pack2(v0, v1);
        }
    }
}

// ---------------- fused: skel update for iter t AND e_{t+2} = E(e_{t+1}) ----------------
// ehalo = e_{t+1} (halo read; both M and E pooled from it).
// eaw = e_t: read pointwise as aimg (INIT: from fp32 fin instead), then overwritten
//            in-place with e_{t+2} (same idx, same thread, load-before-store -> safe).
template<bool INIT, bool WRITE_E, bool DOSIG>
__global__ __launch_bounds__(NT) void fused_kernel(const u16* __restrict__ ehalo,
                                                   u16* __restrict__ eaw,
                                                   const float* __restrict__ fin,
                                                   u16* __restrict__ skel) {
    const int tx2 = threadIdx.x & 31;
    const int ty  = threadIdx.x >> 5;
    const int x0 = blockIdx.x * TX;
    const int y0 = blockIdx.y * TY;
    const int vol = blockIdx.z / NSLAB;
    const int z0 = (blockIdx.z % NSLAB) * ZS;
    const size_t base = (size_t)vol * DHW;
    const float* vin = INIT ? (fin + base) : nullptr;

    __shared__ float raw[TY + 2][TX + 4];
    __shared__ float mnx[TY + 2][TX];
    __shared__ float mxx[TY + 2][TX];

    float n0[2], n1[2], n2[2];   // erosion ring (min)
    float m0[2], m1[2], m2[2];   // dilation ring (max)
    n0[0]=n0[1]=n1[0]=n1[1]=n2[0]=n2[1]=INFINITY;
    m0[0]=m0[1]=m1[0]=m1[1]=m2[0]=m2[1]=-INFINITY;

    for (int zi = z0 - 1; zi <= z0 + ZS; ++zi) {
        const int zl = min(max(zi, 0), DDP - 1);
        const u16* pl = ehalo + base + (size_t)zl * HWP;
        for (int i = threadIdx.x; i < (TY + 2) * ((TX + 4) / 2); i += NT) {
            int ry = i / ((TX + 4) / 2);
            int rx2 = i - ry * ((TX + 4) / 2);
            int gy = y0 + ry - 1; gy = min(max(gy, 0), HH - 1);
            int gx0 = x0 + 2 * rx2 - 2;
            float v0, v1;
            if (gx0 < 0)        { float t = bf2f(pl[(size_t)gy * WW]);          v0 = v1 = t; }
            else if (gx0 >= WW) { float t = bf2f(pl[(size_t)gy * WW + WW - 1]); v0 = v1 = t; }
            else {
                u32 p = *reinterpret_cast<const u32*>(pl + (size_t)gy * WW + gx0);
                v0 = bf2f((u16)p); v1 = bf2f((u16)(p >> 16));
            }
            *reinterpret_cast<float2*>(&raw[ry][2 * rx2]) = make_float2(v0, v1);
        }
        __syncthreads();
        for (int i = threadIdx.x; i < (TY + 2) * TX; i += NT) {
            int ry = i >> 6;
            int rx = i & (TX - 1);
            float a = raw[ry][rx + 1], b = raw[ry][rx + 2], c = raw[ry][rx + 3];
            mnx[ry][rx] = fmin3(a, b, c);
            mxx[ry][rx] = fmax3(a, b, c);
        }
        __syncthreads();
        float2 a0 = *reinterpret_cast<float2*>(&mnx[ty][2 * tx2]);
        float2 a1 = *reinterpret_cast<float2*>(&mnx[ty + 1][2 * tx2]);
        float2 a2 = *reinterpret_cast<float2*>(&mnx[ty + 2][2 * tx2]);
        float2 b0 = *reinterpret_cast<float2*>(&mxx[ty][2 * tx2]);
        float2 b1 = *reinterpret_cast<float2*>(&mxx[ty + 1][2 * tx2]);
        float2 b2 = *reinterpret_cast<float2*>(&mxx[ty + 2][2 * tx2]);
        n0[0]=n1[0]; n1[0]=n2[0]; n2[0]=fmin3(a0.x, a1.x, a2.x);
        n0[1]=n1[1]; n1[1]=n2[1]; n2[1]=fmin3(a0.y, a1.y, a2.y);
        m0[0]=m1[0]; m1[0]=m2[0]; m2[0]=fmax3(b0.x, b1.x, b2.x);
        m0[1]=m1[1]; m1[1]=m2[1]; m2[1]=fmax3(b0.y, b1.y, b2.y);
        if (zi >= z0 + 1) {
            int zc = zi - 1;
            size_t voff = (size_t)zc * HWP + (size_t)(y0 + ty) * WW + x0 + 2 * tx2;
            size_t idx = base + voff;
            float o0 = fmax3(m0[0], m1[0], m2[0]);
            float o1 = fmax3(m0[1], m1[1], m2[1]);
            float av0, av1;
            if (INIT) {
                float2 fv = *reinterpret_cast<const float2*>(vin + voff);
                av0 = fv.x; av1 = fv.y;
                if (DOSIG) { av0 = sigm(av0); av1 = sigm(av1); }
            } else {
                u32 ap = *reinterpret_cast<const u32*>(eaw + idx);
                av0 = bf2f((u16)ap); av1 = bf2f((u16)(ap >> 16));
            }
            float d0 = fmaxf(av0 - o0, 0.f);
            float d1 = fmaxf(av1 - o1, 0.f);
            u32 pk;
            if (INIT) {
                pk = pack2(d0, d1);
            } else {
                u32 sp = *reinterpret_cast<const u32*>(skel + idx);
                float s0 = bf2f((u16)sp), s1 = bf2f((u16)(sp >> 16));
                s0 += fmaxf(d0 - s0 * d0, 0.f);
                s1 += fmaxf(d1 - s1 * d1, 0.f);
                pk = pack2(s0, s1);
            }
            *reinterpret_cast<u32*>(skel + idx) = pk;
            if (WRITE_E) {
                *reinterpret_cast<u32*>(eaw + idx) = pack2(fmin3(n0[0], n1[0], n2[0]),
                                                           fmin3(n0[1], n1[1], n2[1]));
            }
        }
    }
}

// -------- deterministic 2-sum reduction: p0 = sum(skel*f(other)), p1 = sum(skel) --------
template<bool SIG_O>
__global__ __launch_bounds__(256) void reduce2_kernel(const u16* __restrict__ skel,
                                                      const float* __restrict__ other,
                                                      float* __restrict__ p0,
                                                      float* __restrict__ p1) {
    const u32* sk = (const u32*)skel;
    const float2* ot = (const float2*)other;
    float a0 = 0.f, a1 = 0.f;
    for (int i = blockIdx.x * 256 + threadIdx.x; i < N2 / 2; i += gridDim.x * 256) {
        u32 a = sk[i];
        float2 t = ot[i];
        float s0 = bf2f((u16)a), s1 = bf2f((u16)(a >> 16));
        float o0 = SIG_O ? sigm(t.x) : t.x;
        float o1 = SIG_O ? sigm(t.y) : t.y;
        a0 += s0 * o0 + s1 * o1;
        a1 += s0 + s1;
    }
    for (int off = 32; off > 0; off >>= 1) {
        a0 += __shfl_down(a0, off);
        a1 += __shfl_down(a1, off);
    }
    __shared__ float red[4][2];
    int wave = threadIdx.x >> 6;
    if ((threadIdx.x & 63) == 0) { red[wave][0] = a0; red[wave][1] = a1; }
    __syncthreads();
    if (threadIdx.x == 0) {
        float s0 = 0.f, s1 = 0.f;
        for (int w = 0; w < 4; ++w) { s0 += red[w][0]; s1 += red[w][1]; }
        p0[blockIdx.x] = s0;
        p1[blockIdx.x] = s1;
    }
}

__global__ __launch_bounds__(256) void finalize_kernel(const float* __restrict__ part,
                                                       float* __restrict__ out) {
    float a0 = 0.f, a1 = 0.f, a2 = 0.f, a3 = 0.f;
    for (int i = threadIdx.x; i < RED_BLOCKS; i += 256) {
        a0 += part[0 * RED_BLOCKS + i];
        a1 += part[1 * RED_BLOCKS + i];
        a2 += part[2 * RED_BLOCKS + i];
        a3 += part[3 * RED_BLOCKS + i];
    }
    for (int off = 32; off > 0; off >>= 1) {
        a0 += __shfl_down(a0, off);
        a1 += __shfl_down(a1, off);
        a2 += __shfl_down(a2, off);
        a3 += __shfl_down(a3, off);
    }
    __shared__ float red[4][4];
    int wave = threadIdx.x >> 6;
    if ((threadIdx.x & 63) == 0) {
        red[wave][0] = a0; red[wave][1] = a1; red[wave][2] = a2; red[wave][3] = a3;
    }
    __syncthreads();
    if (threadIdx.x == 0) {
        float s0 = 0.f, s1 = 0.f, s2 = 0.f, s3 = 0.f;
        for (int w = 0; w < 4; ++w) {
            s0 += red[w][0]; s1 += red[w][1]; s2 += red[w][2]; s3 += red[w][3];
        }
        float tprec = (s0 + 1.f) / (s1 + 1.f);
        float tsens = (s2 + 1.f) / (s3 + 1.f);
        float cl = 2.f * tprec * tsens / (tprec + tsens + 1.f);
        out[0] = 1.f - cl;
    }
}

__global__ void sentinel_kernel(float* out, float v) { out[0] = v; }

template<bool DOSIG>
static void run_branch(const float* fin, u16* EA, u16* EB, u16* SKEL, hipStream_t stream) {
    dim3 grid(WW / TX, HH / TY, 2 * NSLAB);   // 4 x 32 x 16 = 2048 blocks
    // EB = e_1 = E(f(input))
    erode_init_kernel<DOSIG><<<grid, NT, 0, stream>>>(fin, EB);
    // skel = relu(e_0 - M(e_1));  EA <- e_2 = E(e_1)
    fused_kernel<true, true, DOSIG><<<grid, NT, 0, stream>>>(EB, EA, fin, SKEL);
    u16* h = EA;   // e_2
    u16* a = EB;   // e_1
    for (int t = 1; t <= NITER; ++t) {
        if (t < NITER) fused_kernel<false, true,  false><<<grid, NT, 0, stream>>>(h, a, nullptr, SKEL);
        else           fused_kernel<false, false, false><<<grid, NT, 0, stream>>>(h, a, nullptr, SKEL);
        u16* tmp = h; h = a; a = tmp;
    }
}

extern "C" void kernel_launch(void* const* d_in, const int* in_sizes, int n_in,
                              void* d_out, int out_size, void* d_ws, size_t ws_size,
                              hipStream_t stream) {
    const float* ypred = (const float*)d_in[0];
    const float* ytrue = (const float*)d_in[1];
    float* out = (float*)d_out;

    // 3 bf16 buffers of N2 (75.5 MB) + fp32 partials — fits L3 and proven ws budget.
    const size_t need = (size_t)3 * N2 * sizeof(u16) + (size_t)4 * RED_BLOCKS * sizeof(float);
    if (ws_size < need) {
        sentinel_kernel<<<1, 1, 0, stream>>>(out, -111111.f);
        return;
    }

    u16* EA   = (u16*)d_ws;
    u16* EB   = EA + N2;
    u16* SKEL = EB + N2;
    float* PART = (float*)(SKEL + N2);

    // pred branch: skel_pred from sigmoid(y_pred)
    run_branch<true>(ypred, EA, EB, SKEL, stream);
    reduce2_kernel<false><<<RED_BLOCKS, 256, 0, stream>>>(SKEL, ytrue,
                                                          PART + 0 * RED_BLOCKS,
                                                          PART + 1 * RED_BLOCKS);
    // true branch: skel_true from y_true
    run_branch<false>(ytrue, EA, EB, SKEL, stream);
    reduce2_kernel<true><<<RED_BLOCKS, 256, 0, stream>>>(SKEL, ypred,
                                                         PART + 2 * RED_BLOCKS,
                                                         PART + 3 * RED_BLOCKS);

    finalize_kernel<<<1, 256, 0, stream>>>(PART, out);
}